// Round 12
// baseline (587.474 us; speedup 1.0000x reference)
//
#include <hip/hip_runtime.h>
#include <hip/hip_bf16.h>

// GCN: h1 = relu(Â (x W1) + b1); h2 = relu(Â (h1 W2) + b2);
// out = mean_pool(h2, batch) @ Wlin + blin,  Â = D^-1/2 (A+I) D^-1/2
//
// R2: per-graph counts via sorted-batch boundaries.
// R3: norm folded into gemm epilogue (xws = dinv*xw).
// R5/R6: bucketed CSR build, deterministic two-pass, zero global atomics.
// R7: xws bf16 -> agg row gather 128 B.
// R8/R9 LESSON: sub-dword per-lane global stores defeat L2 write-merge.
// R10: agg v2 -- 2 edges per gather instr. LESSON: gather is instruction/
//     latency-slot bound, not byte bound (halving instrs: 66->54 us).
// R11 LESSON: fusion at 4 nodes/block neutral -- per-block fixed costs
//     (W2 staging 400 MB, barrier max-of-4-degree tail) ate the gains.
// R12: 16 nodes/block fused kernels (W2 staging /4, CLT smooths barrier
//     tail, fixed costs /4) + 4 edges per gather instruction (8 B/lane,
//     quarter-wave per row, shfl_xor(16/32) butterfly merge).

#define NDIM 64
#define NGRAPH 64
#define BSHIFT 7                      // 128 nodes per bucket
#define BNODES 128
#define ECHUNK 8192                   // edges per block in bincnt/bscatter (32/thread)

__device__ __forceinline__ unsigned short f32_to_bf16(float f) {
    unsigned int u = __float_as_uint(f);
    unsigned int r = 0x7FFFu + ((u >> 16) & 1u);   // round-to-nearest-even
    return (unsigned short)((u + r) >> 16);
}

// ---- pass 1: per-(block,bucket) edge counts via LDS histogram ----
__global__ void bincnt_k(const int* __restrict__ dst, int* __restrict__ cntmat,
                         int e, int nb) {
    extern __shared__ int hist[];
    int t = threadIdx.x;
    for (int i = t; i < nb; i += 256) hist[i] = 0;
    __syncthreads();
    int base = blockIdx.x * ECHUNK + t;
#pragma unroll
    for (int k = 0; k < 32; ++k) {
        int i = base + k * 256;
        if (i < e) atomicAdd(&hist[dst[i] >> BSHIFT], 1);   // LDS atomic
    }
    __syncthreads();
    long row = (long)blockIdx.x * nb;
    for (int i = t; i < nb; i += 256) cntmat[row + i] = hist[i];
}

// ---- pass 2: per-bucket exclusive scan across blocks (one block per bucket) ----
__global__ void colscan_k(const int* __restrict__ cntmat, int* __restrict__ basemat,
                          int* __restrict__ bucketTot, int nblk, int nb) {
    __shared__ int s[256];
    int b = blockIdx.x;
    int t = threadIdx.x;
    int v = (t < nblk) ? cntmat[(long)t * nb + b] : 0;
    s[t] = v;
    __syncthreads();
    for (int off = 1; off < 256; off <<= 1) {
        int tmp = (t >= off) ? s[t - off] : 0;
        __syncthreads();
        s[t] += tmp;
        __syncthreads();
    }
    if (t < nblk) basemat[(long)t * nb + b] = s[t] - v;   // exclusive within column
    if (t == 255) bucketTot[b] = s[255];
}

// ---- pass 3: exclusive scan of bucket totals (single block, nb<=1024) ----
__global__ void bscan_k(const int* __restrict__ bucketTot, int* __restrict__ bucketStart,
                        int* __restrict__ start, int nb, int n, int e) {
    __shared__ int s[1024];
    int t = threadIdx.x;
    int v = (t < nb) ? bucketTot[t] : 0;
    s[t] = v;
    __syncthreads();
    for (int off = 1; off < 1024; off <<= 1) {
        int tmp = (t >= off) ? s[t - off] : 0;
        __syncthreads();
        s[t] += tmp;
        __syncthreads();
    }
    if (t < nb) bucketStart[t + 1] = s[t];
    if (t == 0) { bucketStart[0] = 0; start[n] = e; }   // CSR sentinel
}

// ---- pass 4: scatter packed (dst_local<<25 | src) via block-private LDS cursors ----
__global__ void bscatter_k(const int* __restrict__ src, const int* __restrict__ dst,
                           const int* __restrict__ bucketStart,
                           const int* __restrict__ basemat,
                           unsigned int* __restrict__ ebuf, int e, int nb) {
    extern __shared__ int cur[];
    int t = threadIdx.x;
    long row = (long)blockIdx.x * nb;
    for (int i = t; i < nb; i += 256) cur[i] = bucketStart[i] + basemat[row + i];
    __syncthreads();
    int base = blockIdx.x * ECHUNK + t;
#pragma unroll
    for (int k = 0; k < 32; ++k) {
        int i = base + k * 256;
        if (i < e) {
            int d = dst[i];
            int b = d >> BSHIFT;
            int pos = atomicAdd(&cur[b], 1);               // LDS atomic, block-private
            ebuf[pos] = ((unsigned)(d & (BNODES - 1)) << 25) | (unsigned)src[i];
        }
    }
}

// ---- pass 5: one block per bucket -> dst-ordered CSR slice, dinv, graph ranges ----
__global__ void fill2_k(const unsigned int* __restrict__ ebuf,
                        const int* __restrict__ bucketStart,
                        const int* __restrict__ batch, float* __restrict__ dinv,
                        int* __restrict__ start, int* __restrict__ csr,
                        int* __restrict__ gstart, int* __restrict__ gend, int n) {
    __shared__ int scnt[BNODES], sincl[BNODES], scur[BNODES];
    int t = threadIdx.x;
    int b = blockIdx.x;
    int node0 = b << BSHIFT;
    int nNodes = min(BNODES, n - node0);
    if (t < BNODES) scnt[t] = 0;
    int e0 = bucketStart[b], e1 = bucketStart[b + 1];
    __syncthreads();
    for (int i = e0 + t; i < e1; i += 256)
        atomicAdd(&scnt[ebuf[i] >> 25], 1);
    __syncthreads();
    int val = (t < BNODES) ? scnt[t] : 0;
    if (t < BNODES) sincl[t] = val;
    __syncthreads();
    for (int off = 1; off < BNODES; off <<= 1) {
        int tmp = (t >= off && t < BNODES) ? sincl[t - off] : 0;
        __syncthreads();
        if (t < BNODES) sincl[t] += tmp;
        __syncthreads();
    }
    if (t < nNodes) {
        int v = node0 + t;
        int st = e0 + sincl[t] - val;     // exclusive within bucket
        start[v] = st;
        scur[t] = st;
        dinv[v] = rsqrtf((float)(val + 1));
        int g = batch[v];                 // sorted-batch boundary detection
        if (v == 0 || batch[v - 1] != g) gstart[g] = v;
        if (v == n - 1 || batch[v + 1] != g) gend[g] = v + 1;
    }
    __syncthreads();
    for (int i = e0 + t; i < e1; i += 256) {
        unsigned rec = ebuf[i];
        int pos = atomicAdd(&scur[rec >> 25], 1);
        csr[pos] = (int)(rec & 0x1FFFFFFu);   // scatter within L2-local 8 KB slice
    }
}

// ---- dense GEMM  C[n,64](bf16 pairs) = scale[row] * (A[n,64] @ W[64,64]) ----
// 16 rows/block; thread (row=t>>4, cg=t&15) computes cols 4cg..4cg+3.
__global__ void gemm_k(const float* __restrict__ A, const float* __restrict__ W,
                       const float* __restrict__ scale, unsigned int* __restrict__ C,
                       int n) {
    __shared__ float4 Wl4[64 * 16];   // 16 KB: W[k][4c..4c+3]
    __shared__ float  Xl[16 * 64];    //  4 KB
    int t = threadIdx.x;
    const float4* W4 = (const float4*)W;
#pragma unroll
    for (int i = 0; i < 4; ++i) Wl4[t + 256 * i] = W4[t + 256 * i];
    long base = (long)blockIdx.x * 1024;
    long lim  = (long)n * 64;
#pragma unroll
    for (int i = 0; i < 4; ++i) {
        long idx = base + t + 256 * i;
        Xl[t + 256 * i] = (idx < lim) ? A[idx] : 0.f;
    }
    __syncthreads();
    int row = t >> 4, cg = t & 15;
    float ax = 0.f, ay = 0.f, az = 0.f, aw = 0.f;
#pragma unroll
    for (int k = 0; k < 64; ++k) {
        float4 wv = Wl4[k * 16 + cg];
        float  xv = Xl[row * 64 + k];
        ax += xv * wv.x;
        ay += xv * wv.y;
        az += xv * wv.z;
        aw += xv * wv.w;
    }
    int v = blockIdx.x * 16 + row;
    if (v < n) {
        float s = scale[v];
        unsigned int ulo = ((unsigned int)f32_to_bf16(s * ay) << 16) | (unsigned int)f32_to_bf16(s * ax);
        unsigned int uhi = ((unsigned int)f32_to_bf16(s * aw) << 16) | (unsigned int)f32_to_bf16(s * az);
        long dbase = (long)v * (NDIM / 2) + cg * 2;
        C[dbase]     = ulo;
        C[dbase + 1] = uhi;
    }
}

// ---- gather core v3: 4 edges per gather instruction ----
// Lane (q=lane>>4, p=lane&15) loads 8 B (dims 4p..4p+3) of edge i+q.
// Butterfly shfl_xor(16/32) merges quarter-waves; returns dim d=4p+q sum
// (self-loop included, pre-dinv-scale).
__device__ __forceinline__ float gather4(const unsigned long long* __restrict__ xp8,
                                         const int* __restrict__ csr,
                                         int s0, int d0, int q, int p, int v) {
    float a0, a1, a2, a3;
    if (q == 0) {                         // self loop counted once (q==0 only)
        unsigned long long u = xp8[(long)v * 16 + p];
        a0 = __uint_as_float((unsigned int)(u & 0xFFFFu) << 16);
        a1 = __uint_as_float((unsigned int)(u & 0xFFFF0000u));
        a2 = __uint_as_float((unsigned int)((u >> 32) & 0xFFFFu) << 16);
        a3 = __uint_as_float((unsigned int)(u >> 48) << 16);
    } else { a0 = a1 = a2 = a3 = 0.f; }
    float b0 = 0.f, b1 = 0.f, b2 = 0.f, b3 = 0.f;
    int i = 0;
    for (; i + 8 <= d0; i += 8) {         // 2 independent 8 B gathers in flight
        int j0 = csr[s0 + i + q];
        int j1 = csr[s0 + i + 4 + q];
        unsigned long long u0 = xp8[(long)j0 * 16 + p];
        unsigned long long u1 = xp8[(long)j1 * 16 + p];
        a0 += __uint_as_float((unsigned int)(u0 & 0xFFFFu) << 16);
        a1 += __uint_as_float((unsigned int)(u0 & 0xFFFF0000u));
        a2 += __uint_as_float((unsigned int)((u0 >> 32) & 0xFFFFu) << 16);
        a3 += __uint_as_float((unsigned int)(u0 >> 48) << 16);
        b0 += __uint_as_float((unsigned int)(u1 & 0xFFFFu) << 16);
        b1 += __uint_as_float((unsigned int)(u1 & 0xFFFF0000u));
        b2 += __uint_as_float((unsigned int)((u1 >> 32) & 0xFFFFu) << 16);
        b3 += __uint_as_float((unsigned int)(u1 >> 48) << 16);
    }
    for (; i + 4 <= d0; i += 4) {
        int j = csr[s0 + i + q];
        unsigned long long u = xp8[(long)j * 16 + p];
        a0 += __uint_as_float((unsigned int)(u & 0xFFFFu) << 16);
        a1 += __uint_as_float((unsigned int)(u & 0xFFFF0000u));
        a2 += __uint_as_float((unsigned int)((u >> 32) & 0xFFFFu) << 16);
        a3 += __uint_as_float((unsigned int)(u >> 48) << 16);
    }
    if (q < d0 - i) {                     // remainder 0..3 edges
        int j = csr[s0 + i + q];
        unsigned long long u = xp8[(long)j * 16 + p];
        a0 += __uint_as_float((unsigned int)(u & 0xFFFFu) << 16);
        a1 += __uint_as_float((unsigned int)(u & 0xFFFF0000u));
        a2 += __uint_as_float((unsigned int)((u >> 32) & 0xFFFFu) << 16);
        a3 += __uint_as_float((unsigned int)(u >> 48) << 16);
    }
    a0 += b0; a1 += b1; a2 += b2; a3 += b3;
    a0 += __shfl_xor(a0, 16); a0 += __shfl_xor(a0, 32);
    a1 += __shfl_xor(a1, 16); a1 += __shfl_xor(a1, 32);
    a2 += __shfl_xor(a2, 16); a2 += __shfl_xor(a2, 32);
    a3 += __shfl_xor(a3, 16); a3 += __shfl_xor(a3, 32);
    return (q == 0) ? a0 : (q == 1) ? a1 : (q == 2) ? a2 : a3;
}

// ---- fused layer1-agg + layer2-gemm:  xws2[v] = dinv[v] * (h1[v] @ W2) ----
// 16 nodes/block (wave gathers 4 sequentially) -> W2 staged once per 16.
__global__ void aggmm_k(const unsigned long long* __restrict__ xp8,
                        const float* __restrict__ dinv,
                        const int* __restrict__ start, const int* __restrict__ csr,
                        const float* __restrict__ b1, const float* __restrict__ W2,
                        unsigned int* __restrict__ xws2, int n) {
    __shared__ float W2l[64 * 64];    // 16 KB
    __shared__ float rows[16][64];    //  4 KB
    __shared__ float dvs[16];
    int t = threadIdx.x;
#pragma unroll
    for (int i = 0; i < 16; ++i) W2l[t + 256 * i] = W2[t + 256 * i];
    int lane = t & 63, wv = t >> 6;
    int q = lane >> 4, p = lane & 15;
    int v0 = blockIdx.x * 16;
    int r0 = wv * 4;
#pragma unroll
    for (int nd = 0; nd < 4; ++nd) {
        int r = r0 + nd;
        int v = v0 + r;
        if (v < n) {
            float dv = dinv[v];
            int s0 = start[v];
            int d0 = start[v + 1] - s0;
            float sum = gather4(xp8, csr, s0, d0, q, p, v);
            int d = 4 * p + q;
            rows[r][d] = fmaxf(sum * dv + b1[d], 0.f);
            if (lane == 0) dvs[r] = dv;
        } else {
            rows[r][lane] = 0.f;
            if (lane == 0) dvs[r] = 0.f;
        }
    }
    __syncthreads();
    float ac0 = 0.f, ac1 = 0.f, ac2 = 0.f, ac3 = 0.f;
#pragma unroll
    for (int k = 0; k < 64; ++k) {
        float w = W2l[k * 64 + lane];          // stride-1: 2-way, free
        ac0 += rows[r0 + 0][k] * w;            // wave-uniform broadcasts
        ac1 += rows[r0 + 1][k] * w;
        ac2 += rows[r0 + 2][k] * w;
        ac3 += rows[r0 + 3][k] * w;
    }
    bool even = ((lane & 1) == 0);
    int half = lane >> 1;
    float m0 = dvs[r0 + 0] * ac0;
    float o0 = __shfl_xor(m0, 1);
    if (even && v0 + r0 + 0 < n)
        xws2[(long)(v0 + r0 + 0) * 32 + half] = ((unsigned int)f32_to_bf16(o0) << 16) | (unsigned int)f32_to_bf16(m0);
    float m1 = dvs[r0 + 1] * ac1;
    float o1 = __shfl_xor(m1, 1);
    if (even && v0 + r0 + 1 < n)
        xws2[(long)(v0 + r0 + 1) * 32 + half] = ((unsigned int)f32_to_bf16(o1) << 16) | (unsigned int)f32_to_bf16(m1);
    float m2 = dvs[r0 + 2] * ac2;
    float o2 = __shfl_xor(m2, 1);
    if (even && v0 + r0 + 2 < n)
        xws2[(long)(v0 + r0 + 2) * 32 + half] = ((unsigned int)f32_to_bf16(o2) << 16) | (unsigned int)f32_to_bf16(m2);
    float m3 = dvs[r0 + 3] * ac3;
    float o3 = __shfl_xor(m3, 1);
    if (even && v0 + r0 + 3 < n)
        xws2[(long)(v0 + r0 + 3) * 32 + half] = ((unsigned int)f32_to_bf16(o3) << 16) | (unsigned int)f32_to_bf16(m3);
}

// ---- fused layer2-agg + mean-pool accumulation (16 nodes/block) ----
__global__ void aggpool_k(const unsigned long long* __restrict__ xp8,
                          const float* __restrict__ dinv,
                          const int* __restrict__ start, const int* __restrict__ csr,
                          const float* __restrict__ b2, const int* __restrict__ batch,
                          float* __restrict__ pooled, int n) {
    __shared__ float rows[16][64];
    __shared__ int gs[16];
    int t = threadIdx.x;
    int lane = t & 63, wv = t >> 6;
    int q = lane >> 4, p = lane & 15;
    int v0 = blockIdx.x * 16;
    int r0 = wv * 4;
#pragma unroll
    for (int nd = 0; nd < 4; ++nd) {
        int r = r0 + nd;
        int v = v0 + r;
        if (v < n) {
            int s0 = start[v];
            int d0 = start[v + 1] - s0;
            float sum = gather4(xp8, csr, s0, d0, q, p, v);
            int d = 4 * p + q;
            rows[r][d] = fmaxf(sum * dinv[v] + b2[d], 0.f);
            if (lane == 0) gs[r] = batch[v];
        } else {
            rows[r][lane] = 0.f;
            if (lane == 0) gs[r] = -1;
        }
    }
    __syncthreads();
    if (t < 64) {                          // batch sorted: few flushes
        int gcur = -1;
        float acc = 0.f;
        for (int w = 0; w < 16; ++w) {
            int g = gs[w];
            if (g < 0) continue;
            if (g != gcur) {
                if (gcur >= 0) atomicAdd(&pooled[gcur * NDIM + t], acc);
                gcur = g;
                acc = 0.f;
            }
            acc += rows[w][t];
        }
        if (gcur >= 0) atomicAdd(&pooled[gcur * NDIM + t], acc);
    }
}

// ---- head: out[g,c] = (pooled[g,:]/max(cnt,1)) @ Wlin + blin ----
__global__ void final_k(const float* __restrict__ pooled, const int* __restrict__ gstart,
                        const int* __restrict__ gend,
                        const float* __restrict__ Wlin, const float* __restrict__ blin,
                        float* __restrict__ out, int nclass) {
    int t = blockIdx.x * blockDim.x + threadIdx.x;
    if (t >= NGRAPH * nclass) return;
    int g = t / nclass, c = t % nclass;
    float cnt = (float)(gend[g] - gstart[g]);
    float inv = 1.f / fmaxf(cnt, 1.f);
    float acc = 0.f;
    for (int j = 0; j < NDIM; ++j) acc += pooled[g * NDIM + j] * Wlin[j * nclass + c];
    out[t] = acc * inv + blin[c];
}

extern "C" void kernel_launch(void* const* d_in, const int* in_sizes, int n_in,
                              void* d_out, int out_size, void* d_ws, size_t ws_size,
                              hipStream_t stream) {
    const float* x     = (const float*)d_in[0];
    const int*   ei    = (const int*)d_in[1];
    const int*   batch = (const int*)d_in[2];
    const float* W1    = (const float*)d_in[3];
    const float* b1    = (const float*)d_in[4];
    const float* W2    = (const float*)d_in[5];
    const float* b2    = (const float*)d_in[6];
    const float* Wlin  = (const float*)d_in[7];
    const float* blin  = (const float*)d_in[8];
    float* out = (float*)d_out;

    const int N = in_sizes[0] / NDIM;        // 100000
    const int E = in_sizes[1] / 2;           // 1600000
    const int NCLASS = in_sizes[7] / NDIM;   // 10
    const int* src = ei;
    const int* dst = ei + E;
    const int NB   = (N + BNODES - 1) >> BSHIFT;        // 782 buckets (<=1024)
    const int NBLK = (E + ECHUNK - 1) / ECHUNK;         // 196 edge blocks (<=256)

    // ---- workspace carve-out (each 256B-aligned) ----
    size_t o = 0;
    char* wsp = (char*)d_ws;
    auto take = [&](size_t nbytes) -> void* {
        void* p = (void*)(wsp + o);
        o += (nbytes + 255) & ~(size_t)255;
        return p;
    };
    int*   gstart    = (int*)take(NGRAPH * 4);
    int*   gend      = (int*)take(NGRAPH * 4);
    float* pooled    = (float*)take(NGRAPH * NDIM * 4);
    size_t zero_bytes = o;                    // everything above must start at 0
    int*   cntmat   = (int*)take((size_t)NBLK * NB * 4);
    int*   basemat  = (int*)take((size_t)NBLK * NB * 4);
    int*   bucketTot   = (int*)take((size_t)NB * 4);
    int*   bucketStart = (int*)take((size_t)(NB + 1) * 4);
    float* dinv  = (float*)take((size_t)N * 4);
    int*   start = (int*)take((size_t)(N + 1) * 4);
    int*   csr   = (int*)take((size_t)E * 4);
    unsigned int* ebuf = (unsigned int*)take((size_t)E * 4);
    unsigned int* xws1 = (unsigned int*)take((size_t)N * NDIM * 2);   // bf16 pairs
    unsigned int* xws2 = (unsigned int*)take((size_t)N * NDIM * 2);   // bf16 pairs
    (void)ws_size;

    hipMemsetAsync(d_ws, 0, zero_bytes, stream);

    int fbl = (N + 15) / 16;                  // 16 nodes per block (fused kernels)
    int gbl = (N + 15) / 16;                  // 16 rows per block (gemm)

    // CSR build (deterministic two-pass binning, zero global atomics)
    bincnt_k<<<NBLK, 256, (size_t)NB * 4, stream>>>(dst, cntmat, E, NB);
    colscan_k<<<NB, 256, 0, stream>>>(cntmat, basemat, bucketTot, NBLK, NB);
    bscan_k<<<1, 1024, 0, stream>>>(bucketTot, bucketStart, start, NB, N, E);
    bscatter_k<<<NBLK, 256, (size_t)NB * 4, stream>>>(src, dst, bucketStart, basemat, ebuf, E, NB);
    fill2_k<<<NB, 256, 0, stream>>>(ebuf, bucketStart, batch, dinv, start, csr, gstart, gend, N);

    // layer 1 gemm: xws1 = dinv * (x @ W1)  [bf16 pairs]
    gemm_k<<<gbl, 256, 0, stream>>>(x, W1, dinv, xws1, N);
    // fused: agg layer1 + gemm layer2 -> xws2 = dinv * (h1 @ W2)
    aggmm_k<<<fbl, 256, 0, stream>>>((const unsigned long long*)xws1, dinv, start, csr, b1, W2, xws2, N);
    // fused: agg layer2 + mean-pool accumulation
    aggpool_k<<<fbl, 256, 0, stream>>>((const unsigned long long*)xws2, dinv, start, csr, b2, batch, pooled, N);
    // head
    final_k<<<(NGRAPH * NCLASS + 255) / 256, 256, 0, stream>>>(pooled, gstart, gend, Wlin, blin, out, NCLASS);
}

// Round 13
// 319.259 us; speedup vs baseline: 1.8401x; 1.8401x over previous
//
#include <hip/hip_runtime.h>
#include <hip/hip_bf16.h>

// GCN: h1 = relu(Â (x W1) + b1); h2 = relu(Â (h1 W2) + b2);
// out = mean_pool(h2, batch) @ Wlin + blin,  Â = D^-1/2 (A+I) D^-1/2
//
// R2: per-graph counts via sorted-batch boundaries.
// R3: norm folded into gemm epilogue (xws = dinv*xw).
// R5/R6: bucketed CSR build, deterministic two-pass, zero global atomics.
// R7: xws bf16 -> agg row gather 128 B.
// R8/R9 LESSON: sub-dword per-lane global stores defeat L2 write-merge.
// R10: agg v2 -- 2 edges per gather instr (instruction-bound, not byte-bound).
// R11 LESSON: W2-gemm fusion at 4 nodes/block neutral (per-block W2 staging
//     + barrier tail ate the gain). aggpool fusion was clean.
// R12 LESSON: 4x-unrolled multi-node gather spilled to scratch (VGPR 24->64,
//     FETCH/WRITE +0.5/+0.9 GB). Keep ONE gather context live per wave.
// R13: re-anchor on R10 (324 us measured) + keep only the aggpool fusion.

#define NDIM 64
#define NGRAPH 64
#define BSHIFT 7                      // 128 nodes per bucket
#define BNODES 128
#define ECHUNK 8192                   // edges per block in bincnt/bscatter (32/thread)

__device__ __forceinline__ unsigned short f32_to_bf16(float f) {
    unsigned int u = __float_as_uint(f);
    unsigned int r = 0x7FFFu + ((u >> 16) & 1u);   // round-to-nearest-even
    return (unsigned short)((u + r) >> 16);
}

// ---- pass 1: per-(block,bucket) edge counts via LDS histogram ----
__global__ void bincnt_k(const int* __restrict__ dst, int* __restrict__ cntmat,
                         int e, int nb) {
    extern __shared__ int hist[];
    int t = threadIdx.x;
    for (int i = t; i < nb; i += 256) hist[i] = 0;
    __syncthreads();
    int base = blockIdx.x * ECHUNK + t;
#pragma unroll
    for (int k = 0; k < 32; ++k) {
        int i = base + k * 256;
        if (i < e) atomicAdd(&hist[dst[i] >> BSHIFT], 1);   // LDS atomic
    }
    __syncthreads();
    long row = (long)blockIdx.x * nb;
    for (int i = t; i < nb; i += 256) cntmat[row + i] = hist[i];
}

// ---- pass 2: per-bucket exclusive scan across blocks (one block per bucket) ----
__global__ void colscan_k(const int* __restrict__ cntmat, int* __restrict__ basemat,
                          int* __restrict__ bucketTot, int nblk, int nb) {
    __shared__ int s[256];
    int b = blockIdx.x;
    int t = threadIdx.x;
    int v = (t < nblk) ? cntmat[(long)t * nb + b] : 0;
    s[t] = v;
    __syncthreads();
    for (int off = 1; off < 256; off <<= 1) {
        int tmp = (t >= off) ? s[t - off] : 0;
        __syncthreads();
        s[t] += tmp;
        __syncthreads();
    }
    if (t < nblk) basemat[(long)t * nb + b] = s[t] - v;   // exclusive within column
    if (t == 255) bucketTot[b] = s[255];
}

// ---- pass 3: exclusive scan of bucket totals (single block, nb<=1024) ----
__global__ void bscan_k(const int* __restrict__ bucketTot, int* __restrict__ bucketStart,
                        int* __restrict__ start, int nb, int n, int e) {
    __shared__ int s[1024];
    int t = threadIdx.x;
    int v = (t < nb) ? bucketTot[t] : 0;
    s[t] = v;
    __syncthreads();
    for (int off = 1; off < 1024; off <<= 1) {
        int tmp = (t >= off) ? s[t - off] : 0;
        __syncthreads();
        s[t] += tmp;
        __syncthreads();
    }
    if (t < nb) bucketStart[t + 1] = s[t];
    if (t == 0) { bucketStart[0] = 0; start[n] = e; }   // CSR sentinel
}

// ---- pass 4: scatter packed (dst_local<<25 | src) via block-private LDS cursors ----
__global__ void bscatter_k(const int* __restrict__ src, const int* __restrict__ dst,
                           const int* __restrict__ bucketStart,
                           const int* __restrict__ basemat,
                           unsigned int* __restrict__ ebuf, int e, int nb) {
    extern __shared__ int cur[];
    int t = threadIdx.x;
    long row = (long)blockIdx.x * nb;
    for (int i = t; i < nb; i += 256) cur[i] = bucketStart[i] + basemat[row + i];
    __syncthreads();
    int base = blockIdx.x * ECHUNK + t;
#pragma unroll
    for (int k = 0; k < 32; ++k) {
        int i = base + k * 256;
        if (i < e) {
            int d = dst[i];
            int b = d >> BSHIFT;
            int pos = atomicAdd(&cur[b], 1);               // LDS atomic, block-private
            ebuf[pos] = ((unsigned)(d & (BNODES - 1)) << 25) | (unsigned)src[i];
        }
    }
}

// ---- pass 5: one block per bucket -> dst-ordered CSR slice, dinv, graph ranges ----
__global__ void fill2_k(const unsigned int* __restrict__ ebuf,
                        const int* __restrict__ bucketStart,
                        const int* __restrict__ batch, float* __restrict__ dinv,
                        int* __restrict__ start, int* __restrict__ csr,
                        int* __restrict__ gstart, int* __restrict__ gend, int n) {
    __shared__ int scnt[BNODES], sincl[BNODES], scur[BNODES];
    int t = threadIdx.x;
    int b = blockIdx.x;
    int node0 = b << BSHIFT;
    int nNodes = min(BNODES, n - node0);
    if (t < BNODES) scnt[t] = 0;
    int e0 = bucketStart[b], e1 = bucketStart[b + 1];
    __syncthreads();
    for (int i = e0 + t; i < e1; i += 256)
        atomicAdd(&scnt[ebuf[i] >> 25], 1);
    __syncthreads();
    int val = (t < BNODES) ? scnt[t] : 0;
    if (t < BNODES) sincl[t] = val;
    __syncthreads();
    for (int off = 1; off < BNODES; off <<= 1) {
        int tmp = (t >= off && t < BNODES) ? sincl[t - off] : 0;
        __syncthreads();
        if (t < BNODES) sincl[t] += tmp;
        __syncthreads();
    }
    if (t < nNodes) {
        int v = node0 + t;
        int st = e0 + sincl[t] - val;     // exclusive within bucket
        start[v] = st;
        scur[t] = st;
        dinv[v] = rsqrtf((float)(val + 1));
        int g = batch[v];                 // sorted-batch boundary detection
        if (v == 0 || batch[v - 1] != g) gstart[g] = v;
        if (v == n - 1 || batch[v + 1] != g) gend[g] = v + 1;
    }
    __syncthreads();
    for (int i = e0 + t; i < e1; i += 256) {
        unsigned rec = ebuf[i];
        int pos = atomicAdd(&scur[rec >> 25], 1);
        csr[pos] = (int)(rec & 0x1FFFFFFu);   // scatter within L2-local 8 KB slice
    }
}

// ---- dense GEMM  C[n,64](bf16 pairs) = scale[row] * (A[n,64] @ W[64,64]) ----
// 16 rows/block; thread (row=t>>4, cg=t&15) computes cols 4cg..4cg+3.
__global__ void gemm_k(const float* __restrict__ A, const float* __restrict__ W,
                       const float* __restrict__ scale, unsigned int* __restrict__ C,
                       int n) {
    __shared__ float4 Wl4[64 * 16];   // 16 KB: W[k][4c..4c+3]
    __shared__ float  Xl[16 * 64];    //  4 KB
    int t = threadIdx.x;
    const float4* W4 = (const float4*)W;
#pragma unroll
    for (int i = 0; i < 4; ++i) Wl4[t + 256 * i] = W4[t + 256 * i];
    long base = (long)blockIdx.x * 1024;
    long lim  = (long)n * 64;
#pragma unroll
    for (int i = 0; i < 4; ++i) {
        long idx = base + t + 256 * i;
        Xl[t + 256 * i] = (idx < lim) ? A[idx] : 0.f;
    }
    __syncthreads();
    int row = t >> 4, cg = t & 15;
    float ax = 0.f, ay = 0.f, az = 0.f, aw = 0.f;
#pragma unroll
    for (int k = 0; k < 64; ++k) {
        float4 wv = Wl4[k * 16 + cg];
        float  xv = Xl[row * 64 + k];
        ax += xv * wv.x;
        ay += xv * wv.y;
        az += xv * wv.z;
        aw += xv * wv.w;
    }
    int v = blockIdx.x * 16 + row;
    if (v < n) {
        float s = scale[v];
        unsigned int ulo = ((unsigned int)f32_to_bf16(s * ay) << 16) | (unsigned int)f32_to_bf16(s * ax);
        unsigned int uhi = ((unsigned int)f32_to_bf16(s * aw) << 16) | (unsigned int)f32_to_bf16(s * az);
        long dbase = (long)v * (NDIM / 2) + cg * 2;
        C[dbase]     = ulo;
        C[dbase + 1] = uhi;
    }
}

// ---- gather core (R10-proven): 2 edges per gather instruction ----
// lane covers dim pair p=lane&31 via dword (2 bf16); half-wave h=lane>>5
// handles edges i+h. Returns value for dim d = 2p+h (self-loop included).
__device__ __forceinline__ float gather_row(const unsigned int* __restrict__ xp,
                                            const int* __restrict__ csr,
                                            int s0, int d0, int h, int p, int v) {
    float l0 = 0.f, l1 = 0.f, l2 = 0.f, l3 = 0.f;
    float h0 = 0.f, h1 = 0.f, h2 = 0.f, h3 = 0.f;
    int i = 0;
    for (; i + 8 <= d0; i += 8) {
        int j0 = csr[s0 + i + 0 + h];
        int j1 = csr[s0 + i + 2 + h];
        int j2 = csr[s0 + i + 4 + h];
        int j3 = csr[s0 + i + 6 + h];
        unsigned int u0 = xp[(long)j0 * 32 + p];
        unsigned int u1 = xp[(long)j1 * 32 + p];
        unsigned int u2 = xp[(long)j2 * 32 + p];
        unsigned int u3 = xp[(long)j3 * 32 + p];
        l0 += __uint_as_float(u0 << 16);  h0 += __uint_as_float(u0 & 0xFFFF0000u);
        l1 += __uint_as_float(u1 << 16);  h1 += __uint_as_float(u1 & 0xFFFF0000u);
        l2 += __uint_as_float(u2 << 16);  h2 += __uint_as_float(u2 & 0xFFFF0000u);
        l3 += __uint_as_float(u3 << 16);  h3 += __uint_as_float(u3 & 0xFFFF0000u);
    }
    for (; i + 2 <= d0; i += 2) {
        int j = csr[s0 + i + h];
        unsigned int u = xp[(long)j * 32 + p];
        l0 += __uint_as_float(u << 16);
        h0 += __uint_as_float(u & 0xFFFF0000u);
    }
    if (i < d0 && h == 0) {               // odd leftover edge: half-wave 0 only
        int j = csr[s0 + i];
        unsigned int u = xp[(long)j * 32 + p];
        l0 += __uint_as_float(u << 16);
        h0 += __uint_as_float(u & 0xFFFF0000u);
    }
    float al = (l0 + l1) + (l2 + l3);
    float ah = (h0 + h1) + (h2 + h3);
    al += __shfl_xor(al, 32);             // merge the two half-waves
    ah += __shfl_xor(ah, 32);
    unsigned int us = xp[(long)v * 32 + p];   // self loop
    al += __uint_as_float(us << 16);
    ah += __uint_as_float(us & 0xFFFF0000u);
    return h ? ah : al;
}

// ---- aggregation (layer 1): out[v,:] = relu( dinv[v]*gather + b ), f32 out ----
__global__ void agg_k(const unsigned int* __restrict__ xp, const float* __restrict__ dinv,
                      const int* __restrict__ start, const int* __restrict__ csr,
                      const float* __restrict__ bias, float* __restrict__ out, int n) {
    int t = threadIdx.x;
    int lane = t & 63;
    int h = lane >> 5;
    int p = lane & 31;
    int v = blockIdx.x * 4 + (t >> 6);
    if (v >= n) return;
    int s0 = start[v];
    int d0 = start[v + 1] - s0;
    float sum = gather_row(xp, csr, s0, d0, h, p, v);
    int d = 2 * p + h;
    float val = sum * dinv[v] + bias[d];
    out[(long)v * NDIM + d] = fmaxf(val, 0.f);
}

// ---- fused layer2-agg + mean-pool accumulation (R11-proven clean) ----
__global__ void aggpool_k(const unsigned int* __restrict__ xp, const float* __restrict__ dinv,
                          const int* __restrict__ start, const int* __restrict__ csr,
                          const float* __restrict__ b2, const int* __restrict__ batch,
                          float* __restrict__ pooled, int n) {
    __shared__ float rows[4][64];
    __shared__ int gs[4];
    int t = threadIdx.x;
    int lane = t & 63;
    int wv = t >> 6;
    int h = lane >> 5, p = lane & 31;
    int v = blockIdx.x * 4 + wv;
    bool valid = (v < n);
    if (valid) {
        int s0 = start[v];
        int d0 = start[v + 1] - s0;
        float sum = gather_row(xp, csr, s0, d0, h, p, v);
        int d = 2 * p + h;
        rows[wv][d] = fmaxf(sum * dinv[v] + b2[d], 0.f);
        if (lane == 0) gs[wv] = batch[v];
    } else {
        rows[wv][lane] = 0.f;
        if (lane == 0) gs[wv] = -1;
    }
    __syncthreads();
    if (t < 64) {
        int g0 = gs[0];
        if (g0 >= 0 && g0 == gs[1] && g0 == gs[2] && g0 == gs[3]) {
            float s = (rows[0][t] + rows[1][t]) + (rows[2][t] + rows[3][t]);
            atomicAdd(&pooled[g0 * NDIM + t], s);      // one row-atomic per block
        } else {
            for (int w = 0; w < 4; ++w) {
                int g = gs[w];
                if (g >= 0) atomicAdd(&pooled[g * NDIM + t], rows[w][t]);
            }
        }
    }
}

// ---- head: out[g,c] = (pooled[g,:]/max(cnt,1)) @ Wlin + blin ----
__global__ void final_k(const float* __restrict__ pooled, const int* __restrict__ gstart,
                        const int* __restrict__ gend,
                        const float* __restrict__ Wlin, const float* __restrict__ blin,
                        float* __restrict__ out, int nclass) {
    int t = blockIdx.x * blockDim.x + threadIdx.x;
    if (t >= NGRAPH * nclass) return;
    int g = t / nclass, c = t % nclass;
    float cnt = (float)(gend[g] - gstart[g]);
    float inv = 1.f / fmaxf(cnt, 1.f);
    float acc = 0.f;
    for (int j = 0; j < NDIM; ++j) acc += pooled[g * NDIM + j] * Wlin[j * nclass + c];
    out[t] = acc * inv + blin[c];
}

extern "C" void kernel_launch(void* const* d_in, const int* in_sizes, int n_in,
                              void* d_out, int out_size, void* d_ws, size_t ws_size,
                              hipStream_t stream) {
    const float* x     = (const float*)d_in[0];
    const int*   ei    = (const int*)d_in[1];
    const int*   batch = (const int*)d_in[2];
    const float* W1    = (const float*)d_in[3];
    const float* b1    = (const float*)d_in[4];
    const float* W2    = (const float*)d_in[5];
    const float* b2    = (const float*)d_in[6];
    const float* Wlin  = (const float*)d_in[7];
    const float* blin  = (const float*)d_in[8];
    float* out = (float*)d_out;

    const int N = in_sizes[0] / NDIM;        // 100000
    const int E = in_sizes[1] / 2;           // 1600000
    const int NCLASS = in_sizes[7] / NDIM;   // 10
    const int* src = ei;
    const int* dst = ei + E;
    const int NB   = (N + BNODES - 1) >> BSHIFT;        // 782 buckets (<=1024)
    const int NBLK = (E + ECHUNK - 1) / ECHUNK;         // 196 edge blocks (<=256)

    // ---- workspace carve-out (each 256B-aligned) ----
    size_t o = 0;
    char* wsp = (char*)d_ws;
    auto take = [&](size_t nbytes) -> void* {
        void* p = (void*)(wsp + o);
        o += (nbytes + 255) & ~(size_t)255;
        return p;
    };
    int*   gstart    = (int*)take(NGRAPH * 4);
    int*   gend      = (int*)take(NGRAPH * 4);
    float* pooled    = (float*)take(NGRAPH * NDIM * 4);
    size_t zero_bytes = o;                    // everything above must start at 0
    int*   cntmat   = (int*)take((size_t)NBLK * NB * 4);
    int*   basemat  = (int*)take((size_t)NBLK * NB * 4);
    int*   bucketTot   = (int*)take((size_t)NB * 4);
    int*   bucketStart = (int*)take((size_t)(NB + 1) * 4);
    float* dinv  = (float*)take((size_t)N * 4);
    int*   start = (int*)take((size_t)(N + 1) * 4);
    int*   csr   = (int*)take((size_t)E * 4);
    unsigned int* ebuf = (unsigned int*)take((size_t)E * 4);
    unsigned int* xws  = (unsigned int*)take((size_t)N * NDIM * 2);   // bf16 pairs
    float* h     = (float*)take((size_t)N * NDIM * 4);
    (void)ws_size;

    hipMemsetAsync(d_ws, 0, zero_bytes, stream);

    int rbl = (N + 3) / 4;                    // 4 nodes per block (agg/aggpool)
    int gbl = (N + 15) / 16;                  // 16 rows per block (gemm)

    // CSR build (deterministic two-pass binning, zero global atomics)
    bincnt_k<<<NBLK, 256, (size_t)NB * 4, stream>>>(dst, cntmat, E, NB);
    colscan_k<<<NB, 256, 0, stream>>>(cntmat, basemat, bucketTot, NBLK, NB);
    bscan_k<<<1, 1024, 0, stream>>>(bucketTot, bucketStart, start, NB, N, E);
    bscatter_k<<<NBLK, 256, (size_t)NB * 4, stream>>>(src, dst, bucketStart, basemat, ebuf, E, NB);
    fill2_k<<<NB, 256, 0, stream>>>(ebuf, bucketStart, batch, dinv, start, csr, gstart, gend, N);

    // layer 1
    gemm_k<<<gbl, 256, 0, stream>>>(x, W1, dinv, xws, N);
    agg_k<<<rbl, 256, 0, stream>>>(xws, dinv, start, csr, b1, h, N);
    // layer 2
    gemm_k<<<gbl, 256, 0, stream>>>(h, W2, dinv, xws, N);
    // fused layer2-agg + mean-pool
    aggpool_k<<<rbl, 256, 0, stream>>>(xws, dinv, start, csr, b2, batch, pooled, N);
    // head
    final_k<<<(NGRAPH * NCLASS + 255) / 256, 256, 0, stream>>>(pooled, gstart, gend, Wlin, blin, out, NCLASS);
}